// Round 6
// baseline (1412.802 us; speedup 1.0000x reference)
//
#include <hip/hip_runtime.h>
#include <math.h>

#define NB    4
#define PP    1024
#define MAXIT 30
#define NBLKS 256
#define BTHR  256
#define AGENT __HIP_MEMORY_SCOPE_AGENT

// Persistent-kernel state. Barrier counters are MONOTONIC across calls/replays
// (epoch base re-read at kernel start); all other state is rewritten each call.
__device__ unsigned g_cnt[16 * 16];   // 16 group counters, 64 B apart
__device__ unsigned g_root;
__device__ unsigned g_epoch;
__device__ float    g_u[NB * PP], g_v[NB * PP];
__device__ double   g_errpart[NBLKS];
__device__ unsigned g_doneflag;
__device__ double   g_costpart[NBLKS];

// Two-level global barrier: 256 blocks -> 16 groups x 16. Monotonic counters;
// `target` = base + local step. Release/acquire chain makes all prior stores
// (drained by __syncthreads' vmcnt(0)) visible to every block on exit.
__device__ __forceinline__ void gbar(unsigned target, int tid, int blk)
{
    __syncthreads();
    if (tid == 0) {
        const unsigned old = __hip_atomic_fetch_add(&g_cnt[(blk & 15) << 4], 1u,
                                                    __ATOMIC_ACQ_REL, AGENT);
        if (old == target * 16u + 15u) {                 // last in group
            const unsigned o2 = __hip_atomic_fetch_add(&g_root, 1u,
                                                       __ATOMIC_ACQ_REL, AGENT);
            if (o2 == target * 16u + 15u)                // last group
                __hip_atomic_store(&g_epoch, target + 1u, __ATOMIC_RELEASE, AGENT);
        }
        while (__hip_atomic_load(&g_epoch, __ATOMIC_ACQUIRE, AGENT) <= target)
            __builtin_amdgcn_s_sleep(2);
    }
    __syncthreads();
}

// ---------------------------------------------------------------------------
// One persistent kernel. Block b: batch n = b>>6, rows/cols [p0, p0+16),
// p0 = (b&63)*16. Each wave owns 4 rows (Creg) and 4 cols (Ctreg); lane l
// covers the 16 global columns/rows q = l + 64k.
// ---------------------------------------------------------------------------
__global__ __launch_bounds__(BTHR, 1)
void sinkhorn_kernel(const float* __restrict__ x, const float* __restrict__ y,
                     const float* __restrict__ xw, const float* __restrict__ yw,
                     float* __restrict__ out)
{
    const int tid = threadIdx.x, lane = tid & 63, wid = tid >> 6;
    const int blk = blockIdx.x;
    const int n = blk >> 6, nbase = n << 10;
    const int p0 = (blk & 63) << 4;

    const unsigned base = __hip_atomic_load(&g_epoch, __ATOMIC_RELAXED, AGENT);
    unsigned ls = 0;

    __shared__ float  xs[16][32], ys[16][32];
    __shared__ double sred[4], dred[4];

    // ---- global weight sums (deterministic, identical in every block) ----
    double sx = 0.0, sy = 0.0;
    for (int i = tid; i < NB * PP; i += BTHR) { sx += (double)xw[i]; sy += (double)yw[i]; }
#pragma unroll
    for (int o = 32; o; o >>= 1) { sx += __shfl_xor(sx, o); sy += __shfl_xor(sy, o); }
    if (lane == 0) { sred[wid] = sx; dred[wid] = sy; }
    __syncthreads();
    const double Sx = ((sred[0] + sred[1]) + sred[2]) + sred[3];
    const double Sy = ((dred[0] + dred[1]) + dred[2]) + dred[3];
    __syncthreads();

    // ---- stage own 16 x-rows / 16 y-cols ----
    for (int i = tid; i < 16 * 32; i += BTHR) {
        xs[i >> 5][i & 31] = x[((size_t)(nbase + p0 + (i >> 5)) << 5) + (i & 31)];
        ys[i >> 5][i & 31] = y[((size_t)(nbase + p0 + (i >> 5)) << 5) + (i & 31)];
    }
    __syncthreads();

    // per-own-row |x|^2, |y|^2 and log-weights
    float x2r[4], y2r[4], lmu[4], lnu[4];
#pragma unroll
    for (int rr = 0; rr < 4; ++rr) {
        const int wr = (wid << 2) + rr;
        float ax = 0.f, ay = 0.f;
#pragma unroll
        for (int d = 0; d < 32; ++d) {
            ax = fmaf(xs[wr][d], xs[wr][d], ax);
            ay = fmaf(ys[wr][d], ys[wr][d], ay);
        }
        x2r[rr] = ax; y2r[rr] = ay;
        lmu[rr] = (float)log((double)xw[nbase + p0 + wr] / Sx + 1e-8);
        lnu[rr] = (float)log((double)yw[nbase + p0 + wr] / Sy + 1e-8);
    }

    // ---- build Creg (4 rows x 16 cols/lane) and Ctreg (4 cols x 16 rows/lane)
    float Creg[4][16], Ctreg[4][16];
#pragma unroll 1
    for (int k = 0; k < 16; ++k) {
        const int q = lane + (k << 6);
        float pv[32];
        // y-point q -> Creg[.][k]
        {
            const float4* yp = reinterpret_cast<const float4*>(y + ((size_t)(nbase + q) << 5));
#pragma unroll
            for (int j = 0; j < 8; ++j) {
                const float4 f = yp[j];
                pv[4*j+0] = f.x; pv[4*j+1] = f.y; pv[4*j+2] = f.z; pv[4*j+3] = f.w;
            }
            float y2q = 0.f;
#pragma unroll
            for (int d = 0; d < 32; ++d) y2q = fmaf(pv[d], pv[d], y2q);
#pragma unroll
            for (int rr = 0; rr < 4; ++rr) {
                const int wr = (wid << 2) + rr;
                float dot = 0.f;
#pragma unroll
                for (int d = 0; d < 32; ++d) dot = fmaf(xs[wr][d], pv[d], dot);
                Creg[rr][k] = x2r[rr] + y2q - 2.f * dot;
            }
        }
        // x-point q -> Ctreg[.][k]
        {
            const float4* xp = reinterpret_cast<const float4*>(x + ((size_t)(nbase + q) << 5));
#pragma unroll
            for (int j = 0; j < 8; ++j) {
                const float4 f = xp[j];
                pv[4*j+0] = f.x; pv[4*j+1] = f.y; pv[4*j+2] = f.z; pv[4*j+3] = f.w;
            }
            float x2q = 0.f;
#pragma unroll
            for (int d = 0; d < 32; ++d) x2q = fmaf(pv[d], pv[d], x2q);
#pragma unroll
            for (int rr = 0; rr < 4; ++rr) {
                const int wr = (wid << 2) + rr;
                float dot = 0.f;
#pragma unroll
                for (int d = 0; d < 32; ++d) dot = fmaf(ys[wr][d], pv[d], dot);
                Ctreg[rr][k] = x2q + y2r[rr] - 2.f * dot;
            }
        }
    }

    // ---- Sinkhorn loop ----
    float vv[16], uu[16];
#pragma unroll
    for (int k = 0; k < 16; ++k) vv[k] = 0.f;
    float ureg[4] = {0.f, 0.f, 0.f, 0.f};
    float vreg[4] = {0.f, 0.f, 0.f, 0.f};
    int done = 0;

    for (int it = 0; it < MAXIT; ++it) {
        if (it) {
#pragma unroll
            for (int k = 0; k < 16; ++k)
                vv[k] = __hip_atomic_load(&g_v[nbase + lane + (k << 6)], __ATOMIC_RELAXED, AGENT);
        }
        // -- u-phase: u_new[p] = 0.1*(log_mu[p] - lse_q((v[q]-C[p,q])*10))
        double du = 0.0;
        float myu = 0.f;
#pragma unroll
        for (int rr = 0; rr < 4; ++rr) {
            float tv[16], mx = -1e30f;
#pragma unroll
            for (int k = 0; k < 16; ++k) { tv[k] = (vv[k] - Creg[rr][k]) * 10.f; mx = fmaxf(mx, tv[k]); }
#pragma unroll
            for (int o = 32; o; o >>= 1) mx = fmaxf(mx, __shfl_xor(mx, o));
            float s = 0.f;
#pragma unroll
            for (int k = 0; k < 16; ++k) s += __expf(tv[k] - mx);
#pragma unroll
            for (int o = 32; o; o >>= 1) s += __shfl_xor(s, o);
            const float un = 0.1f * (lmu[rr] - (mx + __logf(s)));
            du += fabs((double)un - (double)ureg[rr]);   // err uses u_new vs old (always)
            if (!done) ureg[rr] = un;                    // freeze semantics
            if (lane == rr) myu = ureg[rr];              // rr is compile-time (unrolled)
        }
        if (lane < 4)
            __hip_atomic_store(&g_u[nbase + p0 + (wid << 2) + lane], myu, __ATOMIC_RELAXED, AGENT);
        if (lane == 0) dred[wid] = du;
        __syncthreads();
        if (tid == 0)
            __hip_atomic_store(&g_errpart[blk], ((dred[0] + dred[1]) + dred[2]) + dred[3],
                               __ATOMIC_RELAXED, AGENT);

        gbar(base + ls, tid, blk); ++ls;     // u + err partials visible

        // block 0: deterministic err total -> done flag for it+1 (read after barrier B)
        if (blk == 0) {
            double ep = __hip_atomic_load(&g_errpart[tid], __ATOMIC_RELAXED, AGENT);
#pragma unroll
            for (int o = 32; o; o >>= 1) ep += __shfl_xor(ep, o);
            if (lane == 0) sred[wid] = ep;
            __syncthreads();
            if (tid == 0) {
                const double tot = ((sred[0] + sred[1]) + sred[2]) + sred[3];
                __hip_atomic_store(&g_doneflag, (unsigned)(done | (tot < 0.4)),
                                   __ATOMIC_RELAXED, AGENT);     // total<0.4 <=> mean<0.1
            }
        }

        // -- v-phase: v_new[q] = 0.1*(log_nu[q] - lse_p((u[p]-C[p,q])*10))
#pragma unroll
        for (int k = 0; k < 16; ++k)
            uu[k] = __hip_atomic_load(&g_u[nbase + lane + (k << 6)], __ATOMIC_RELAXED, AGENT);
        float myv = 0.f;
#pragma unroll
        for (int rr = 0; rr < 4; ++rr) {
            float tv[16], mx = -1e30f;
#pragma unroll
            for (int k = 0; k < 16; ++k) { tv[k] = (uu[k] - Ctreg[rr][k]) * 10.f; mx = fmaxf(mx, tv[k]); }
#pragma unroll
            for (int o = 32; o; o >>= 1) mx = fmaxf(mx, __shfl_xor(mx, o));
            float s = 0.f;
#pragma unroll
            for (int k = 0; k < 16; ++k) s += __expf(tv[k] - mx);
#pragma unroll
            for (int o = 32; o; o >>= 1) s += __shfl_xor(s, o);
            const float vn = 0.1f * (lnu[rr] - (mx + __logf(s)));
            if (!done) vreg[rr] = vn;
            if (lane == rr) myv = vreg[rr];
        }
        if (lane < 4)
            __hip_atomic_store(&g_v[nbase + p0 + (wid << 2) + lane], myv, __ATOMIC_RELAXED, AGENT);

        gbar(base + ls, tid, blk); ++ls;     // v + done flag visible

        done = (int)__hip_atomic_load(&g_doneflag, __ATOMIC_RELAXED, AGENT);
        if (done) break;                      // frozen forever after -> remaining iters are no-ops
    }

    // ---- cost = sum_pq exp((u_p + v_q - C_pq)*10) * C_pq, per batch ----
#pragma unroll
    for (int k = 0; k < 16; ++k)
        vv[k] = __hip_atomic_load(&g_v[nbase + lane + (k << 6)], __ATOMIC_RELAXED, AGENT);
    double part = 0.0;
#pragma unroll
    for (int rr = 0; rr < 4; ++rr) {
#pragma unroll
        for (int k = 0; k < 16; ++k) {
            const float c = Creg[rr][k];
            part += (double)__expf((ureg[rr] + vv[k] - c) * 10.f) * (double)c;
        }
    }
#pragma unroll
    for (int o = 32; o; o >>= 1) part += __shfl_xor(part, o);
    if (lane == 0) dred[wid] = part;
    __syncthreads();
    if (tid == 0)
        __hip_atomic_store(&g_costpart[blk], ((dred[0] + dred[1]) + dred[2]) + dred[3],
                           __ATOMIC_RELAXED, AGENT);

    gbar(base + ls, tid, blk); ++ls;         // cost partials visible

    if (blk < NB && tid < 64) {              // block n reduces its batch's 64 partials
        double s2 = __hip_atomic_load(&g_costpart[(blk << 6) + tid], __ATOMIC_RELAXED, AGENT);
#pragma unroll
        for (int o = 32; o; o >>= 1) s2 += __shfl_xor(s2, o);
        if (tid == 0) out[blk] = (float)s2;
    }
}

// ---------------------------------------------------------------------------
extern "C" void kernel_launch(void* const* d_in, const int* in_sizes, int n_in,
                              void* d_out, int out_size, void* d_ws, size_t ws_size,
                              hipStream_t stream)
{
    (void)in_sizes; (void)n_in; (void)out_size; (void)d_ws; (void)ws_size;
    const float* x  = (const float*)d_in[0];
    const float* y  = (const float*)d_in[1];
    const float* xw = (const float*)d_in[2];
    const float* yw = (const float*)d_in[3];
    float* out = (float*)d_out;

    hipLaunchKernelGGL(sinkhorn_kernel, dim3(NBLKS), dim3(BTHR), 0, stream,
                       x, y, xw, yw, out);
}

// Round 8
// 358.367 us; speedup vs baseline: 3.9423x; 3.9423x over previous
//
#include <hip/hip_runtime.h>
#include <math.h>

#define NB    4
#define PP    1024
#define DD    32
#define MAXIT 30
#define PBLK  1024    // phase grid: 1 row per wave, 4 rows/block
#define BTHR  256

// delta = (C - rowmin) stored as u16 fixed point, range [0, 240]
#define DRANGE 240.0f
#define QSCL   (65535.0f / DRANGE)          // C-delta -> u16
#define DS10   (10.0f * DRANGE / 65535.0f)  // u16 -> 10*C-delta (exponent units)
#define DS1    (DRANGE / 65535.0f)          // u16 -> C-delta

// Module-scope device state; rewritten every call (no d_ws dependence).
__device__ unsigned short g_Kd [NB*PP*PP];  // delta rows (x-major), 8 MB
__device__ unsigned short g_Ktd[NB*PP*PP];  // delta rows of C^T (y-major), 8 MB
__device__ float  g_rmin[NB*PP], g_cmin[NB*PP];
__device__ float  g_logmu[NB*PP], g_lognu[NB*PP];
__device__ float  g_u[NB*PP], g_v[NB*PP];
__device__ double g_errpart[MAXIT*PBLK];
__device__ int    g_done[MAXIT+1];
__device__ double g_costpart[PBLK];

// ---------------------------------------------------------------------------
__global__ __launch_bounds__(BTHR)
void prep_kernel(const float* __restrict__ xw, const float* __restrict__ yw)
{
    const int t = threadIdx.x, lane = t & 63, wid = t >> 6;
    double sx = 0.0, sy = 0.0;
    for (int i = t; i < NB*PP; i += BTHR) { sx += (double)xw[i]; sy += (double)yw[i]; }
#pragma unroll
    for (int o = 32; o > 0; o >>= 1) { sx += __shfl_xor(sx, o); sy += __shfl_xor(sy, o); }
    __shared__ double a[4], b[4];
    if (lane == 0) { a[wid] = sx; b[wid] = sy; }
    __syncthreads();
    const double Sx = ((a[0]+a[1])+a[2])+a[3];
    const double Sy = ((b[0]+b[1])+b[2])+b[3];
    for (int i = t; i < NB*PP; i += BTHR) {
        g_logmu[i] = (float)log((double)xw[i]/Sx + 1e-8);
        g_lognu[i] = (float)log((double)yw[i]/Sy + 1e-8);
        g_u[i] = 0.f;
        g_v[i] = 0.f;
    }
    if (t <= MAXIT) g_done[t] = 0;
}

// ---------------------------------------------------------------------------
// Build quantized C-deltas. Blocks 0..511: rows of C (x vs all y) -> g_Kd;
// blocks 512..1023: rows of C^T (y vs all x) -> g_Ktd. Block owns 8 rows;
// thread t owns cols {t, t+256, t+512, t+768} in registers (no scratch).
__global__ __launch_bounds__(BTHR)
void build_kernel(const float* __restrict__ x, const float* __restrict__ y)
{
    const int t = threadIdx.x, lane = t & 63, wid = t >> 6;
    const int bid = blockIdx.x;
    const bool isK = bid < 512;
    const int b = isK ? bid : bid - 512;     // 0..511
    const int n = b >> 7;
    const int nbase = n << 10;
    const int gr0 = b << 3;

    __shared__ float rows[8][DD];
    {
        const int r = t >> 5, d = t & 31;
        const float* src = isK ? x : y;
        rows[r][d] = src[(gr0 + r) * DD + d];
    }
    __syncthreads();

    const float* other = isK ? y : x;

    const float4* op0 = reinterpret_cast<const float4*>(other + ((size_t)(nbase + t      ) << 5));
    const float4* op1 = reinterpret_cast<const float4*>(other + ((size_t)(nbase + t + 256) << 5));
    const float4* op2 = reinterpret_cast<const float4*>(other + ((size_t)(nbase + t + 512) << 5));
    const float4* op3 = reinterpret_cast<const float4*>(other + ((size_t)(nbase + t + 768) << 5));

    float acc0[8], acc1[8], acc2[8], acc3[8];
#pragma unroll
    for (int r = 0; r < 8; ++r) { acc0[r]=0.f; acc1[r]=0.f; acc2[r]=0.f; acc3[r]=0.f; }

#pragma unroll
    for (int j = 0; j < 8; ++j) {
        const float4 f0 = op0[j], f1 = op1[j], f2 = op2[j], f3 = op3[j];
#pragma unroll
        for (int r = 0; r < 8; ++r) {
            const float4 rv = *reinterpret_cast<const float4*>(&rows[r][4*j]);
            float d;
            d = rv.x-f0.x; acc0[r]=fmaf(d,d,acc0[r]);
            d = rv.y-f0.y; acc0[r]=fmaf(d,d,acc0[r]);
            d = rv.z-f0.z; acc0[r]=fmaf(d,d,acc0[r]);
            d = rv.w-f0.w; acc0[r]=fmaf(d,d,acc0[r]);
            d = rv.x-f1.x; acc1[r]=fmaf(d,d,acc1[r]);
            d = rv.y-f1.y; acc1[r]=fmaf(d,d,acc1[r]);
            d = rv.z-f1.z; acc1[r]=fmaf(d,d,acc1[r]);
            d = rv.w-f1.w; acc1[r]=fmaf(d,d,acc1[r]);
            d = rv.x-f2.x; acc2[r]=fmaf(d,d,acc2[r]);
            d = rv.y-f2.y; acc2[r]=fmaf(d,d,acc2[r]);
            d = rv.z-f2.z; acc2[r]=fmaf(d,d,acc2[r]);
            d = rv.w-f2.w; acc2[r]=fmaf(d,d,acc2[r]);
            d = rv.x-f3.x; acc3[r]=fmaf(d,d,acc3[r]);
            d = rv.y-f3.y; acc3[r]=fmaf(d,d,acc3[r]);
            d = rv.z-f3.z; acc3[r]=fmaf(d,d,acc3[r]);
            d = rv.w-f3.w; acc3[r]=fmaf(d,d,acc3[r]);
        }
    }

    // block-wide row minima (8 rows)
    __shared__ float mred[4][8];
    __shared__ float rmin[8];
    float tmin[8];
#pragma unroll
    for (int r = 0; r < 8; ++r)
        tmin[r] = fminf(fminf(acc0[r], acc1[r]), fminf(acc2[r], acc3[r]));
#pragma unroll
    for (int o = 32; o > 0; o >>= 1) {
#pragma unroll
        for (int r = 0; r < 8; ++r) tmin[r] = fminf(tmin[r], __shfl_xor(tmin[r], o));
    }
    if (lane == 0) {
#pragma unroll
        for (int r = 0; r < 8; ++r) mred[wid][r] = tmin[r];
    }
    __syncthreads();
    if (t < 8) {
        const float m = fminf(fminf(mred[0][t], mred[1][t]), fminf(mred[2][t], mred[3][t]));
        rmin[t] = m;
        if (isK) g_rmin[gr0 + t] = m; else g_cmin[gr0 + t] = m;
    }
    __syncthreads();

    unsigned short* dst = isK ? g_Kd : g_Ktd;
#pragma unroll
    for (int r = 0; r < 8; ++r) {
        unsigned short* row = dst + (((size_t)(gr0 + r)) << 10);
        const float m = rmin[r];
        row[t      ] = (unsigned short)fminf(65535.f, roundf((acc0[r] - m) * QSCL));
        row[t + 256] = (unsigned short)fminf(65535.f, roundf((acc1[r] - m) * QSCL));
        row[t + 512] = (unsigned short)fminf(65535.f, roundf((acc2[r] - m) * QSCL));
        row[t + 768] = (unsigned short)fminf(65535.f, roundf((acc3[r] - m) * QSCL));
    }
}

// ---------------------------------------------------------------------------
// Robust row lse over quantized deltas: tv = 10*v_q - delta; max-subtracted.
// u_new = 0.1*logmu + rmin_p - 0.1*(mx + log s).  1 row/wave, 1024 blocks.
__global__ __launch_bounds__(BTHR)
void u_kernel(int it)
{
    if (g_done[it]) return;
    const int t = threadIdx.x, lane = t & 63, wid = t >> 6;
    const int b = blockIdx.x;
    const int gr = (b << 2) + wid;
    const int nbase = (gr >> 10) << 10;

    // 10*v for this lane's 16 columns [16*lane, 16*lane+16)
    const float4* vp = reinterpret_cast<const float4*>(g_v + nbase + (lane << 4));
    float vv10[16];
#pragma unroll
    for (int k = 0; k < 4; ++k) {
        const float4 f = vp[k];
        vv10[4*k+0] = f.x * 10.f; vv10[4*k+1] = f.y * 10.f;
        vv10[4*k+2] = f.z * 10.f; vv10[4*k+3] = f.w * 10.f;
    }
    const uint4* kp = reinterpret_cast<const uint4*>(g_Kd + (((size_t)gr) << 10) + (lane << 4));
    float tv[16];
#pragma unroll
    for (int h = 0; h < 2; ++h) {
        const uint4 raw = kp[h];
        const unsigned w0 = raw.x, w1 = raw.y, w2 = raw.z, w3 = raw.w;
        const int i = h << 3;
        tv[i+0] = fmaf(-DS10, (float)(w0 & 0xffffu), vv10[i+0]);
        tv[i+1] = fmaf(-DS10, (float)(w0 >> 16),     vv10[i+1]);
        tv[i+2] = fmaf(-DS10, (float)(w1 & 0xffffu), vv10[i+2]);
        tv[i+3] = fmaf(-DS10, (float)(w1 >> 16),     vv10[i+3]);
        tv[i+4] = fmaf(-DS10, (float)(w2 & 0xffffu), vv10[i+4]);
        tv[i+5] = fmaf(-DS10, (float)(w2 >> 16),     vv10[i+5]);
        tv[i+6] = fmaf(-DS10, (float)(w3 & 0xffffu), vv10[i+6]);
        tv[i+7] = fmaf(-DS10, (float)(w3 >> 16),     vv10[i+7]);
    }
    float mx = -1e30f;
#pragma unroll
    for (int i = 0; i < 16; ++i) mx = fmaxf(mx, tv[i]);
#pragma unroll
    for (int o = 32; o > 0; o >>= 1) mx = fmaxf(mx, __shfl_xor(mx, o));
    float s = 0.f;
#pragma unroll
    for (int i = 0; i < 16; ++i) s += __expf(tv[i] - mx);
#pragma unroll
    for (int o = 32; o > 0; o >>= 1) s += __shfl_xor(s, o);

    const float unew = 0.1f * g_logmu[gr] + g_rmin[gr] - 0.1f * (mx + __logf(s));

    __shared__ double dred[4];
    if (lane == 0) {
        dred[wid] = fabs((double)unew - (double)g_u[gr]);
        g_u[gr] = unew;
    }
    __syncthreads();
    if (t == 0) g_errpart[(size_t)it * PBLK + b] = ((dred[0]+dred[1])+dred[2])+dred[3];
}

// ---------------------------------------------------------------------------
// v-phase (same shape, Ct deltas). Block 0 finalizes err(it) -> g_done[it+1].
__global__ __launch_bounds__(BTHR)
void v_kernel(int it)
{
    const int t = threadIdx.x, lane = t & 63, wid = t >> 6;
    const int b = blockIdx.x;
    const int done = g_done[it];

    if (done) {
        if (b == 0 && t == 0) g_done[it + 1] = 1;   // keep latch flowing
        return;
    }

    if (b == 0) {   // err total from u-phase partials -> done flag for it+1
        const double* p = g_errpart + (size_t)it * PBLK;
        double s2 = ((p[t] + p[t+256]) + p[t+512]) + p[t+768];
#pragma unroll
        for (int o = 32; o > 0; o >>= 1) s2 += __shfl_xor(s2, o);
        __shared__ double sred[4];
        if (lane == 0) sred[wid] = s2;
        __syncthreads();
        if (t == 0) {
            const double tot = ((sred[0]+sred[1])+sred[2])+sred[3];
            g_done[it + 1] = (tot < 0.4);    // total<0.4 <=> mean<0.1
        }
    }

    const int gr = (b << 2) + wid;
    const int nbase = (gr >> 10) << 10;

    const float4* up = reinterpret_cast<const float4*>(g_u + nbase + (lane << 4));
    float uu10[16];
#pragma unroll
    for (int k = 0; k < 4; ++k) {
        const float4 f = up[k];
        uu10[4*k+0] = f.x * 10.f; uu10[4*k+1] = f.y * 10.f;
        uu10[4*k+2] = f.z * 10.f; uu10[4*k+3] = f.w * 10.f;
    }
    const uint4* kp = reinterpret_cast<const uint4*>(g_Ktd + (((size_t)gr) << 10) + (lane << 4));
    float tv[16];
#pragma unroll
    for (int h = 0; h < 2; ++h) {
        const uint4 raw = kp[h];
        const unsigned w0 = raw.x, w1 = raw.y, w2 = raw.z, w3 = raw.w;
        const int i = h << 3;
        tv[i+0] = fmaf(-DS10, (float)(w0 & 0xffffu), uu10[i+0]);
        tv[i+1] = fmaf(-DS10, (float)(w0 >> 16),     uu10[i+1]);
        tv[i+2] = fmaf(-DS10, (float)(w1 & 0xffffu), uu10[i+2]);
        tv[i+3] = fmaf(-DS10, (float)(w1 >> 16),     uu10[i+3]);
        tv[i+4] = fmaf(-DS10, (float)(w2 & 0xffffu), uu10[i+4]);
        tv[i+5] = fmaf(-DS10, (float)(w2 >> 16),     uu10[i+5]);
        tv[i+6] = fmaf(-DS10, (float)(w3 & 0xffffu), uu10[i+6]);
        tv[i+7] = fmaf(-DS10, (float)(w3 >> 16),     uu10[i+7]);
    }
    float mx = -1e30f;
#pragma unroll
    for (int i = 0; i < 16; ++i) mx = fmaxf(mx, tv[i]);
#pragma unroll
    for (int o = 32; o > 0; o >>= 1) mx = fmaxf(mx, __shfl_xor(mx, o));
    float s = 0.f;
#pragma unroll
    for (int i = 0; i < 16; ++i) s += __expf(tv[i] - mx);
#pragma unroll
    for (int o = 32; o > 0; o >>= 1) s += __shfl_xor(s, o);

    const float vnew = 0.1f * g_lognu[gr] + g_cmin[gr] - 0.1f * (mx + __logf(s));
    if (lane == 0) g_v[gr] = vnew;
}

// ---------------------------------------------------------------------------
// cost: C = rmin_p + delta;  pi = exp(10(u_p - rmin_p) + 10 v_q - 10*delta).
__global__ __launch_bounds__(BTHR)
void cost_kernel()
{
    const int t = threadIdx.x, lane = t & 63, wid = t >> 6;
    const int b = blockIdx.x;
    const int gr = (b << 2) + wid;
    const int nbase = (gr >> 10) << 10;

    const float rm = g_rmin[gr];
    const float A  = (g_u[gr] - rm) * 10.f;

    const float4* vp = reinterpret_cast<const float4*>(g_v + nbase + (lane << 4));
    float vv10[16];
#pragma unroll
    for (int k = 0; k < 4; ++k) {
        const float4 f = vp[k];
        vv10[4*k+0] = f.x * 10.f; vv10[4*k+1] = f.y * 10.f;
        vv10[4*k+2] = f.z * 10.f; vv10[4*k+3] = f.w * 10.f;
    }
    const uint4* kp = reinterpret_cast<const uint4*>(g_Kd + (((size_t)gr) << 10) + (lane << 4));
    double part = 0.0;
#pragma unroll
    for (int h = 0; h < 2; ++h) {
        const uint4 raw = kp[h];
        const unsigned ws[4] = { raw.x, raw.y, raw.z, raw.w };
#pragma unroll
        for (int j = 0; j < 4; ++j) {
            const float d0 = (float)(ws[j] & 0xffffu);
            const float d1 = (float)(ws[j] >> 16);
            const int i = (h << 3) + (j << 1);
            const float c0 = fmaf(DS1, d0, rm);
            const float c1 = fmaf(DS1, d1, rm);
            part += (double)__expf(A + fmaf(-DS10, d0, vv10[i  ])) * (double)c0;
            part += (double)__expf(A + fmaf(-DS10, d1, vv10[i+1])) * (double)c1;
        }
    }
#pragma unroll
    for (int o = 32; o > 0; o >>= 1) part += __shfl_xor(part, o);
    __shared__ double red[4];
    if (lane == 0) red[wid] = part;
    __syncthreads();
    if (t == 0) g_costpart[b] = ((red[0]+red[1])+red[2])+red[3];
}

__global__ __launch_bounds__(64)
void out_kernel(float* __restrict__ out)
{
    const int t = threadIdx.x;   // 64 threads
#pragma unroll 1
    for (int n = 0; n < NB; ++n) {
        const double* cp = g_costpart + (n << 8);
        double s = ((cp[t] + cp[t+64]) + cp[t+128]) + cp[t+192];
#pragma unroll
        for (int o = 32; o > 0; o >>= 1) s += __shfl_xor(s, o);
        if (t == 0) out[n] = (float)s;
    }
}

// ---------------------------------------------------------------------------
extern "C" void kernel_launch(void* const* d_in, const int* in_sizes, int n_in,
                              void* d_out, int out_size, void* d_ws, size_t ws_size,
                              hipStream_t stream)
{
    (void)in_sizes; (void)n_in; (void)out_size; (void)d_ws; (void)ws_size;
    const float* x  = (const float*)d_in[0];
    const float* y  = (const float*)d_in[1];
    const float* xw = (const float*)d_in[2];
    const float* yw = (const float*)d_in[3];
    float* out = (float*)d_out;

    hipLaunchKernelGGL(prep_kernel,  dim3(1),    dim3(BTHR), 0, stream, xw, yw);
    hipLaunchKernelGGL(build_kernel, dim3(1024), dim3(BTHR), 0, stream, x, y);
    for (int it = 0; it < MAXIT; ++it) {
        hipLaunchKernelGGL(u_kernel, dim3(PBLK), dim3(BTHR), 0, stream, it);
        hipLaunchKernelGGL(v_kernel, dim3(PBLK), dim3(BTHR), 0, stream, it);
    }
    hipLaunchKernelGGL(cost_kernel, dim3(PBLK), dim3(BTHR), 0, stream);
    hipLaunchKernelGGL(out_kernel,  dim3(1),    dim3(64),   0, stream, out);
}